// Round 4
// baseline (451.893 us; speedup 1.0000x reference)
//
#include <hip/hip_runtime.h>
#include <math.h>

// Sparsemax over rows of a (16384 x 4096) float32 matrix.
//
// Bound: tau >= max(x) - 1, so the support lies in {x : x > max - 1}
// (~14-40 elems for N(0,1) rows). Everything outside the candidate set is
// EXACTLY zero in the output, so:
//   - one wave (64 lanes) owns one row: zero block-level sync at all
//   - the output row is zero-filled immediately (stores overlap the
//     load+solve), then <=CAP candidate positions are fixed up after a
//     vmcnt drain (same-wave same-address store ordering via s_waitcnt)
//   - candidates gather into a per-wave LDS segment (wave-synchronous:
//     s_waitcnt lgkmcnt(0) suffices, no __syncthreads)
//   - tau solved in raw space via the exact one-pass rank formula:
//     C_i = #{j: y_j >= y_i}, S_i = sum{y_j >= y_i};
//     k = max C_i over lanes with 1 + C_i*y_i > S_i; tau = (S_i-1)/C_i.
//     (the reference's max-shift cancels algebraically in raw space)
// Fallback for cnt > CAP (statistically never): per-wave full-row Michelot.

constexpr int N_COLS = 4096;
constexpr int BLOCK = 256;
constexpr int WAVES = BLOCK / 64;        // 4 rows per block
constexpr int CHUNKS = N_COLS / 4 / 64;  // 16 float4 per lane
constexpr int CAP = 64;                  // candidate capacity per row

__global__ __launch_bounds__(BLOCK) void sparsemax_kernel(
    const float* __restrict__ x, float* __restrict__ out) {
  const int w = threadIdx.x >> 6;
  const int lane = threadIdx.x & 63;
  const int row = blockIdx.x * WAVES + w;
  const float4* x4 = (const float4*)(x + (size_t)row * N_COLS);
  float* outr = out + (size_t)row * N_COLS;
  float4* o4 = (float4*)outr;

  __shared__ float s_cand[WAVES][CAP];
  __shared__ int s_pos[WAVES][CAP];
  __shared__ int s_n[WAVES];

  if (lane == 0) s_n[w] = 0;  // same-wave DS ops are in-order vs the atomics

  // ---- issue all row loads (16 KB in flight per wave) ----
  float4 f[CHUNKS];
#pragma unroll
  for (int k = 0; k < CHUNKS; ++k) f[k] = x4[k * 64 + lane];

  // ---- zero-fill output row now; fixed up after the solve ----
  const float4 z4 = make_float4(0.f, 0.f, 0.f, 0.f);
#pragma unroll
  for (int k = 0; k < CHUNKS; ++k) o4[k * 64 + lane] = z4;

  // ---- wave max (raw space) ----
  float m = fmaxf(fmaxf(f[0].x, f[0].y), fmaxf(f[0].z, f[0].w));
#pragma unroll
  for (int k = 1; k < CHUNKS; ++k)
    m = fmaxf(m, fmaxf(fmaxf(f[k].x, f[k].y), fmaxf(f[k].z, f[k].w)));
#pragma unroll
  for (int off = 32; off >= 1; off >>= 1) m = fmaxf(m, __shfl_xor(m, off, 64));

  const float thresh = m - 1.0f;

  // ---- gather candidates (value, element index) into this wave's LDS ----
#pragma unroll
  for (int k = 0; k < CHUNKS; ++k) {
    const int base = (k * 64 + lane) * 4;
    if (f[k].x > thresh) { int i = atomicAdd(&s_n[w], 1); if (i < CAP) { s_cand[w][i] = f[k].x; s_pos[w][i] = base + 0; } }
    if (f[k].y > thresh) { int i = atomicAdd(&s_n[w], 1); if (i < CAP) { s_cand[w][i] = f[k].y; s_pos[w][i] = base + 1; } }
    if (f[k].z > thresh) { int i = atomicAdd(&s_n[w], 1); if (i < CAP) { s_cand[w][i] = f[k].z; s_pos[w][i] = base + 2; } }
    if (f[k].w > thresh) { int i = atomicAdd(&s_n[w], 1); if (i < CAP) { s_cand[w][i] = f[k].w; s_pos[w][i] = base + 3; } }
  }
  // drain this wave's LDS writes; no block barrier needed (per-wave segment)
  __asm__ volatile("s_waitcnt lgkmcnt(0)" ::: "memory");
  const int cnt = s_n[w];

  if (cnt <= CAP) {
    // ---- exact one-pass rank formula on <=64 lane-resident candidates ----
    const bool in = lane < cnt;
    float y = in ? s_cand[w][lane] : 0.0f;
    int pos = in ? s_pos[w][lane] : 0;
    float S = 0.0f, C = 0.0f;
    for (int j = 0; j < cnt; ++j) {  // uniform trip count, uniform index
      float yj = __shfl(y, j, 64);
      if (yj >= y) {
        S += yj;
        C += 1.0f;
      }
    }
    bool ok = in && (1.0f + C * y > S);
    float bc = ok ? C : 0.0f;
    float bt = ok ? (S - 1.0f) / C : 0.0f;
#pragma unroll
    for (int off = 32; off >= 1; off >>= 1) {
      float oc = __shfl_xor(bc, off, 64);
      float ot = __shfl_xor(bt, off, 64);
      if (oc > bc) {
        bc = oc;
        bt = ot;
      }
    }
    const float tau = bt;  // uniform across wave
    // wait for the zero-fill stores to retire, then fix up candidates
    __asm__ volatile("s_waitcnt vmcnt(0)" ::: "memory");
    if (in) outr[pos] = fmaxf(y - tau, 0.0f);
  } else {
    // ---- fallback (statistically never): per-wave full-row Michelot ----
    float s = 0.0f;
#pragma unroll
    for (int k = 0; k < CHUNKS; ++k) s += f[k].x + f[k].y + f[k].z + f[k].w;
#pragma unroll
    for (int off = 32; off >= 1; off >>= 1) s += __shfl_xor(s, off, 64);
    float tau = (s - 1.0f) / (float)N_COLS;
    int prev = N_COLS;
    for (int it = 0; it < 64; ++it) {
      float ss = 0.0f, cc = 0.0f;
#pragma unroll
      for (int k = 0; k < CHUNKS; ++k) {
        if (f[k].x > tau) { ss += f[k].x; cc += 1.0f; }
        if (f[k].y > tau) { ss += f[k].y; cc += 1.0f; }
        if (f[k].z > tau) { ss += f[k].z; cc += 1.0f; }
        if (f[k].w > tau) { ss += f[k].w; cc += 1.0f; }
      }
#pragma unroll
      for (int off = 32; off >= 1; off >>= 1) {
        ss += __shfl_xor(ss, off, 64);
        cc += __shfl_xor(cc, off, 64);
      }
      tau = (ss - 1.0f) / cc;
      int ci = (int)cc;
      if (ci == prev) break;
      prev = ci;
    }
    __asm__ volatile("s_waitcnt vmcnt(0)" ::: "memory");
#pragma unroll
    for (int k = 0; k < CHUNKS; ++k) {
      float4 r;
      r.x = fmaxf(f[k].x - tau, 0.0f);
      r.y = fmaxf(f[k].y - tau, 0.0f);
      r.z = fmaxf(f[k].z - tau, 0.0f);
      r.w = fmaxf(f[k].w - tau, 0.0f);
      o4[k * 64 + lane] = r;
    }
  }
}

extern "C" void kernel_launch(void* const* d_in, const int* in_sizes, int n_in,
                              void* d_out, int out_size, void* d_ws,
                              size_t ws_size, hipStream_t stream) {
  const float* x = (const float*)d_in[0];
  float* out = (float*)d_out;
  const int rows = in_sizes[0] / N_COLS;  // 16384
  sparsemax_kernel<<<rows / WAVES, BLOCK, 0, stream>>>(x, out);
}